// Round 11
// baseline (65.847 us; speedup 1.0000x reference)
//
#include <hip/hip_runtime.h>
#include <hip/hip_bf16.h>

// BasicBlock (ReActNet) fused pipeline, MI355X gfx950.  R11:
// Waves split over K (ci-halves), not och: 8 waves = 4 och-groups x 2 ci-halves.
// Per phase each wave reads A as b64 (DS/CU 672->336 cyc) and 4 B longs
// (B L2 traffic 32->16 KB). Exact-integer LDS reduction merges ci-halves;
// m-ownership (h=0: m0-3, h=1: m4-6) for epilogue1/conv1x1/epilogue2.
// All hot arrays static-indexed (literal-bound macros). setprio around MFMA.

typedef unsigned short u16;
typedef unsigned char  u8;
typedef unsigned int   u32;
typedef unsigned long long u64;
typedef float f32x4 __attribute__((ext_vector_type(4)));
typedef long  long2v __attribute__((ext_vector_type(2)));

#define GLD16(gsrc, ldst) \
  __builtin_amdgcn_global_load_lds((__attribute__((address_space(1))) void*)(gsrc), \
                                   (__attribute__((address_space(3))) void*)(ldst), 16, 0, 0)

__device__ __forceinline__ float b2f(u16 u) {
  union { unsigned int i; float f; } c; c.i = ((unsigned int)u) << 16; return c.f;
}
__device__ __forceinline__ u16 f2b(float f) {
  unsigned int u = __builtin_bit_cast(unsigned int, f);
  unsigned int r = (u + 0x7FFFu + ((u >> 16) & 1u)) >> 16;   // RNE
  return (u16)r;
}
__device__ __forceinline__ u8 f2sign8(float v) {   // fp8 e4m3 of sign(v)
  return (v > 0.f) ? 0x38 : ((v < 0.f) ? 0xB8 : 0x00);
}

// ---- prep(blk<512) + act1(blk>=512) merged (unchanged from R10) ----
__global__ __launch_bounds__(256) void prep_act_kernel(
    const float* __restrict__ w1, const float* __restrict__ w2,
    const float* __restrict__ g1, const float* __restrict__ be1,
    const float* __restrict__ m1, const float* __restrict__ v1,
    const float* __restrict__ g2, const float* __restrict__ be2,
    const float* __restrict__ m2, const float* __restrict__ v2,
    u8* __restrict__ w1T, u8* __restrict__ w2T,
    float* __restrict__ ab,
    float* __restrict__ lossdst, const float* __restrict__ lossin,
    const float* __restrict__ x, const float* __restrict__ b11,
    u8* __restrict__ act1pad)
{
  __shared__ float wrow[2304];
  __shared__ float red[256];
  __shared__ u8 lds8[112 * 64];
  const int t = threadIdx.x;
  const int blk = blockIdx.x;

  if (blk < 512) {   // ================= prep =================
    float s = 0.f;
    if (blk < 256) {
      const int o = blk;
      const float4* src = (const float4*)(w1 + o * 2304);
#pragma unroll
      for (int i = 0; i < 3; ++i) {
        int c = i * 256 + t;
        if (c < 576) {
          float4 v = src[c];
          wrow[c * 4 + 0] = v.x; wrow[c * 4 + 1] = v.y;
          wrow[c * 4 + 2] = v.z; wrow[c * 4 + 3] = v.w;
          s += fabsf(v.x) + fabsf(v.y) + fabsf(v.z) + fabsf(v.w);
        }
      }
    } else {
      const int o = blk - 256;
      float v = w2[o * 256 + t];
      wrow[t] = v;
      s = fabsf(v);
    }
    red[t] = s;
    __syncthreads();
    for (int st = 128; st > 0; st >>= 1) { if (t < st) red[t] += red[t + st]; __syncthreads(); }
    if (blk < 256) {
      const int o = blk;
      for (int it = t; it < 288; it += 256) {
        int tap = it >> 5, ci8 = it & 31;
        u64 pack = 0;
#pragma unroll
        for (int k = 0; k < 8; ++k)
          pack |= ((u64)f2sign8(wrow[(ci8 * 8 + k) * 9 + tap])) << (8 * k);
        *(u64*)(w1T + (size_t)(tap * 32 + ci8) * 2048 + o * 8) = pack;
      }
      if (t == 0) {
        float scale = red[0] / 2304.f;
        float inv = g1[o] / sqrtf(v1[o] + 1e-5f);
        ab[o]       = scale * inv;
        ab[256 + o] = be1[o] - m1[o] * inv;
      }
    } else {
      const int o = blk - 256;
      if (t < 32) {
        u64 pack = 0;
#pragma unroll
        for (int k = 0; k < 8; ++k)
          pack |= ((u64)f2sign8(wrow[t * 8 + k])) << (8 * k);
        *(u64*)(w2T + (size_t)t * 2048 + o * 8) = pack;
      }
      if (t == 0) {
        float scale = red[0] / 256.f;
        float inv = g2[o] / sqrtf(v2[o] + 1e-5f);
        ab[512 + o] = scale * inv;
        ab[768 + o] = be2[o] - m2[o] * inv;
      }
    }
    if (blk == 0 && t == 0) lossdst[0] = lossin[0];
    return;
  }

  // ================= act1 =================
  const int b2i = blk - 512;             // 0..895
  const int pxgrp = b2i % 7;
  const int cgrp  = (b2i / 7) & 3;
  const int img   = b2i / 28;
  const int c0 = cgrp * 64;
  const int p0 = pxgrp * 112;
  const float* xb = x + (size_t)img * 200704;
#pragma unroll
  for (int it = 0; it < 7; ++it) {
    int flat = it * 256 + t;           // c:64 x p4:28
    int c = flat / 28;
    int p = (flat % 28) * 4;
    float4 v4 = *(const float4*)(xb + (size_t)(c0 + c) * 784 + p0 + p);
    float bb = b11[c0 + c];
    lds8[(p + 0) * 64 + c] = f2sign8(v4.x + bb);
    lds8[(p + 1) * 64 + c] = f2sign8(v4.y + bb);
    lds8[(p + 2) * 64 + c] = f2sign8(v4.z + bb);
    lds8[(p + 3) * 64 + c] = f2sign8(v4.w + bb);
  }
  __syncthreads();
#pragma unroll
  for (int it = 0; it < 7; ++it) {
    int flat = it * 256 + t;           // px:112 x c4:16
    int px = flat >> 4;
    int c4 = (flat & 15) * 4;
    u32 v = *(const u32*)(lds8 + px * 64 + c4);
    int pos = (((c4 >> 3) & 3) << 4) | (((c4 >> 5) & 1) << 3) | (c4 & 7);  // pos-permute
    int pr = (px * 293) >> 13;         // px/28
    int pc = px - 28 * pr;
    size_t dst = ((size_t)img * 900 + (size_t)(pxgrp * 4 + 1 + pr) * 30 + 1 + pc) * 256 + c0 + pos;
    *(u32*)(act1pad + dst) = v;
  }
  if (pxgrp == 0 && cgrp == 0) {
    for (int idx = t; idx < 116 * 64; idx += 256) {
      int bp = idx >> 6;
      int l4 = (idx & 63) * 4;
      int br, bc;
      if (bp < 30)      { br = 0;       bc = bp; }
      else if (bp < 60) { br = 29;      bc = bp - 30; }
      else if (bp < 88) { br = bp - 59; bc = 0; }
      else              { br = bp - 87; bc = 29; }
      *(u32*)(act1pad + ((size_t)img * 900 + br * 30 + bc) * 256 + l4) = 0u;
    }
  }
}

// ---------------- fused conv3x3 + conv1x1, ci-split waves ----------------
__global__ __launch_bounds__(512, 1) void fused_kernel(
    const u8* __restrict__ act1pad, const float* __restrict__ x,
    const u8* __restrict__ w1T, const u8* __restrict__ w2T,
    const float* __restrict__ ab,
    const float* __restrict__ b12, const float* __restrict__ a1,
    const float* __restrict__ b13, const float* __restrict__ b21,
    const float* __restrict__ b22, const float* __restrict__ a2,
    const float* __restrict__ b23,
    float* __restrict__ dout)
{
  __shared__ __align__(16) u8 win[46080];   // A-window; then reduction scratch; then act2

  const int t = threadIdx.x;
  const int w = t >> 6;
  const int l = t & 63;
  const int lane16 = l & 15;
  const int lq = l >> 4;
  const int g = w & 3;                 // och group (64 och)
  const int h = w >> 2;                // ci half
  const int pxblk = blockIdx.x;        // 224
  const int img = pxblk / 7;
  const int rowgrp = pxblk % 7;

  float al1[4], bt1[4], pA1[4], pS1[4], pB1[4], p21[4];
  float al2[4], bt2[4], pA2[4], pS2[4], pB2[4];
  int posO[4];
#pragma unroll
  for (int n = 0; n < 4; ++n) {
    int O = g * 64 + n * 16 + lane16;
    al1[n] = ab[O];       bt1[n] = ab[256 + O];
    al2[n] = ab[512 + O]; bt2[n] = ab[768 + O];
    pA1[n] = b12[O]; pS1[n] = a1[O]; pB1[n] = b13[O]; p21[n] = b21[O];
    pA2[n] = b22[O]; pS2[n] = a2[O]; pB2[n] = b23[O];
    posO[n] = (O & 0xC0) | (((O >> 3) & 3) << 4) | (((O >> 5) & 1) << 3) | (O & 7);
  }

  int basepix[7];
#pragma unroll
  for (int m = 0; m < 7; ++m) {
    int pm = m * 16 + lane16;
    int r = (pm * 293) >> 13;          // pm/28
    basepix[m] = r * 30 + (pm - 28 * r);
  }

  char* wl = (char*)win;

  f32x4 acc[7][4];
  f32x4 zero4 = {0.f, 0.f, 0.f, 0.f};
#pragma unroll
  for (int m = 0; m < 7; ++m)
#pragma unroll
    for (int n = 0; n < 4; ++n) acc[m][n] = zero4;

  // ---- prologue: stage pos-ordered window once ----
  const u8* winsrc = act1pad + ((size_t)img * 900 + (size_t)rowgrp * 120) * 256;
#pragma unroll
  for (int i = 0; i < 5; ++i) {
    int c = i * 512 + t;
    int pix = c >> 4, j = c & 15;
    GLD16((const char*)winsrc + pix * 256 + ((j ^ (pix & 15)) << 4), wl + c * 16);
  }
  if (t < 320) {
    int c = 2560 + t;
    int pix = c >> 4, j = c & 15;
    GLD16((const char*)winsrc + pix * 256 + ((j ^ (pix & 15)) << 4), wl + c * 16);
  }
  asm volatile("s_waitcnt vmcnt(0)" ::: "memory");
  __builtin_amdgcn_s_barrier();

  // ---- loaders / compute ----
  auto LOADB3 = [&](long* dst, int s) {       // 4 b64 from global (own ci-half, 4 n)
    int sc = (s < 36) ? s : 0;
    const char* base = (const char*)w1T + (size_t)sc * 16384 + (h * 4 + lq) * 2048;
#pragma unroll
    for (int n = 0; n < 4; ++n)
      dst[n] = *(const long*)(base + (g * 64 + n * 16 + lane16) * 8);
  };
  auto DSA3 = [&](long* dst, int s) {         // 7 ds_read_b64 (own ci-half)
    int sc = (s < 36) ? s : 0;
    int tap = sc >> 2;
    int ti = (tap * 11) >> 5;                 // tap/3
    int tapoff = ti * 30 + (tap - 3 * ti);
    int off = ((sc & 3) << 6) | (lq << 4) | (h << 3);
#pragma unroll
    for (int m = 0; m < 7; ++m) {
      int wp = basepix[m] + tapoff;
      dst[m] = *(const long*)(wl + wp * 256 + (off ^ ((wp & 15) << 4)));
    }
  };
  auto COMP = [&](const long* av, const long* bv) {   // 28 MFMA
    __builtin_amdgcn_s_setprio(1);
#pragma unroll
    for (int m = 0; m < 7; ++m)
#pragma unroll
      for (int n = 0; n < 4; ++n)
        acc[m][n] = __builtin_amdgcn_mfma_f32_16x16x32_fp8_fp8(av[m], bv[n], acc[m][n], 0, 0, 0);
    __builtin_amdgcn_s_setprio(0);
  };

  // ---- conv3x3: 36 phases, A dbuf + B 3-set rotation, no barriers ----
  long A0[7], A1[7];
  long b0[4], b1[4], b2[4];
  DSA3(A0, 0); LOADB3(b0, 0); LOADB3(b1, 1);
#pragma unroll 1
  for (int i = 0; i < 6; ++i) {
    int p = i * 6;
    LOADB3(b2, p + 2); DSA3(A1, p + 1); COMP(A0, b0);
    LOADB3(b0, p + 3); DSA3(A0, p + 2); COMP(A1, b1);
    LOADB3(b1, p + 4); DSA3(A1, p + 3); COMP(A0, b2);
    LOADB3(b2, p + 5); DSA3(A0, p + 4); COMP(A1, b0);
    LOADB3(b0, p + 6); DSA3(A1, p + 5); COMP(A0, b1);
    LOADB3(b1, p + 7); DSA3(A0, p + 6); COMP(A1, b2);
  }
  __syncthreads();                     // window reads done; win becomes scratch

  // ---- exact-integer reduction: merge ci-halves; lane-major conflict-free scratch ----
  float* scr = (float*)win;            // 4 g-groups x 8 slots x 64 lanes x 16B = 32 KB
#define RED_CHUNK(MA, CNT, WH)                                                   \
  do {                                                                           \
    if (h == (WH)) {                                                             \
      _Pragma("unroll") for (int mi = 0; mi < (CNT); ++mi)                       \
        _Pragma("unroll") for (int n = 0; n < 4; ++n)                            \
          *(f32x4*)((char*)scr + g * 8192 + ((mi * 4 + n) * 64 + l) * 16)        \
              = acc[(MA) + mi][n];                                              \
    }                                                                            \
    __syncthreads();                                                             \
    if (h != (WH)) {                                                             \
      _Pragma("unroll") for (int mi = 0; mi < (CNT); ++mi)                       \
        _Pragma("unroll") for (int n = 0; n < 4; ++n) {                          \
          f32x4 o = *(const f32x4*)((char*)scr + g * 8192 +                      \
                                    ((mi * 4 + n) * 64 + l) * 16);               \
          acc[(MA) + mi][n] += o;                                                \
        }                                                                        \
    }                                                                            \
    __syncthreads();                                                             \
  } while (0)

  RED_CHUNK(0, 2, 1);   // h1 writes m0,1 -> h0 owns
  RED_CHUNK(2, 2, 1);   // h1 writes m2,3 -> h0 owns
  RED_CHUNK(4, 2, 0);   // h0 writes m4,5 -> h1 owns
  RED_CHUNK(6, 1, 0);   // h0 writes m6   -> h1 owns
#undef RED_CHUNK

  // ---- tail: epilogue1 + conv1x1 + epilogue2 on owned m-range (static macro) ----
#define TAIL(M0, MCNT)                                                           \
  do {                                                                           \
    u32 pk[MCNT][4][2];                                                          \
    _Pragma("unroll") for (int mi = 0; mi < (MCNT); ++mi) {                      \
      int m = (M0) + mi;                                                         \
      int prow = m * 16 + lq * 4;                                                \
      int hwm = rowgrp * 112 + prow;                                             \
      _Pragma("unroll") for (int n = 0; n < 4; ++n) {                            \
        int O = g * 64 + n * 16 + lane16;                                        \
        float4 xr = *(const float4*)(x + ((size_t)(img * 256 + O) * 784 + hwm)); \
        float xv[4] = {xr.x, xr.y, xr.z, xr.w};                                  \
        _Pragma("unroll") for (int rp = 0; rp < 2; ++rp) {                       \
          float o1v[2];                                                          \
          _Pragma("unroll") for (int hh = 0; hh < 2; ++hh) {                     \
            int reg = rp * 2 + hh;                                               \
            int pix = prow + reg;                                                \
            float v = acc[m][n][reg] * al1[n] + bt1[n] + xv[reg];                \
            float t1 = v + pA1[n];                                               \
            t1 = (t1 > 0.f) ? t1 : pS1[n] * t1;                                  \
            o1v[hh] = t1 + pB1[n];                                               \
            wl[pix * 256 + (posO[n] ^ ((pix & 15) << 4))] =                      \
                f2sign8(o1v[hh] + p21[n]);                                       \
          }                                                                      \
          pk[mi][n][rp] = (u32)f2b(o1v[0]) | ((u32)f2b(o1v[1]) << 16);           \
        }                                                                        \
      }                                                                          \
    }                                                                            \
    asm volatile("s_waitcnt lgkmcnt(0)" ::: "memory");                           \
    __builtin_amdgcn_s_barrier();                                                \
    /* conv1x1: 4 phases, owned m only, 1-deep prefetch */                       \
    f32x4 acc2[MCNT][4];                                                         \
    _Pragma("unroll") for (int mi = 0; mi < (MCNT); ++mi)                        \
      _Pragma("unroll") for (int n = 0; n < 4; ++n) acc2[mi][n] = zero4;         \
    long2v X0[MCNT], X1[MCNT];                                                   \
    long c0[8], c1[8];                                                           \
    auto LB1 = [&](long* dst, int sp) {                                          \
      _Pragma("unroll") for (int n = 0; n < 4; ++n)                              \
        _Pragma("unroll") for (int sl = 0; sl < 2; ++sl)                         \
          dst[n * 2 + sl] = *(const long*)((const char*)w2T +                    \
              (size_t)sp * 16384 + (sl * 4 + lq) * 2048 +                        \
              (g * 64 + n * 16 + lane16) * 8);                                   \
    };                                                                           \
    auto DA1 = [&](long2v* dst, int sp) {                                        \
      int off = (sp << 6) | (lq << 4);                                           \
      _Pragma("unroll") for (int mi = 0; mi < (MCNT); ++mi) {                    \
        int pm = ((M0) + mi) * 16 + lane16;                                      \
        dst[mi] = *(const long2v*)(wl + pm * 256 + (off ^ (lane16 << 4)));       \
      }                                                                          \
    };                                                                           \
    auto CP1 = [&](const long2v* a, const long* bv) {                            \
      __builtin_amdgcn_s_setprio(1);                                             \
      _Pragma("unroll") for (int mi = 0; mi < (MCNT); ++mi)                      \
        _Pragma("unroll") for (int n = 0; n < 4; ++n) {                          \
          acc2[mi][n] = __builtin_amdgcn_mfma_f32_16x16x32_fp8_fp8(              \
              a[mi][0], bv[n * 2 + 0], acc2[mi][n], 0, 0, 0);                    \
          acc2[mi][n] = __builtin_amdgcn_mfma_f32_16x16x32_fp8_fp8(              \
              a[mi][1], bv[n * 2 + 1], acc2[mi][n], 0, 0, 0);                    \
        }                                                                        \
      __builtin_amdgcn_s_setprio(0);                                             \
    };                                                                           \
    DA1(X0, 0); LB1(c0, 0);                                                      \
    DA1(X1, 1); LB1(c1, 1); CP1(X0, c0);                                         \
    DA1(X0, 2); LB1(c0, 2); CP1(X1, c1);                                         \
    DA1(X1, 3); LB1(c1, 3); CP1(X0, c0);                                         \
    CP1(X1, c1);                                                                 \
    /* epilogue 2 */                                                             \
    _Pragma("unroll") for (int mi = 0; mi < (MCNT); ++mi) {                      \
      int m = (M0) + mi;                                                         \
      int hwm = rowgrp * 112 + m * 16 + lq * 4;                                  \
      _Pragma("unroll") for (int n = 0; n < 4; ++n) {                            \
        int O = g * 64 + n * 16 + lane16;                                        \
        float r4v[4];                                                            \
        _Pragma("unroll") for (int rp = 0; rp < 2; ++rp) {                       \
          float res0 = b2f((u16)(pk[mi][n][rp] & 0xFFFF));                       \
          float res1 = b2f((u16)(pk[mi][n][rp] >> 16));                          \
          float v0 = acc2[mi][n][rp * 2 + 0] * al2[n] + bt2[n] + res0;           \
          float v1 = acc2[mi][n][rp * 2 + 1] * al2[n] + bt2[n] + res1;           \
          v0 += pA2[n]; v0 = (v0 > 0.f) ? v0 : pS2[n] * v0;                      \
          v1 += pA2[n]; v1 = (v1 > 0.f) ? v1 : pS2[n] * v1;                      \
          r4v[rp * 2 + 0] = v0 + pB2[n];                                         \
          r4v[rp * 2 + 1] = v1 + pB2[n];                                         \
        }                                                                        \
        float4 r4 = {r4v[0], r4v[1], r4v[2], r4v[3]};                            \
        *(float4*)(dout + ((size_t)(img * 256 + O)) * 784 + hwm) = r4;           \
      }                                                                          \
    }                                                                            \
  } while (0)

  if (h == 0) { TAIL(0, 4); } else { TAIL(4, 3); }
#undef TAIL
}

// ---------------- launcher ----------------
extern "C" void kernel_launch(void* const* d_in, const int* in_sizes, int n_in,
                              void* d_out, int out_size, void* d_ws, size_t ws_size,
                              hipStream_t stream) {
  const float* x    = (const float*)d_in[0];
  const float* loss = (const float*)d_in[1];
  const float* b11  = (const float*)d_in[2];
  const float* b12  = (const float*)d_in[3];
  const float* b13  = (const float*)d_in[4];
  const float* b21  = (const float*)d_in[5];
  const float* b22  = (const float*)d_in[6];
  const float* b23  = (const float*)d_in[7];
  const float* w1   = (const float*)d_in[8];
  const float* w2   = (const float*)d_in[9];
  const float* g1   = (const float*)d_in[10];
  const float* be1  = (const float*)d_in[11];
  const float* m1   = (const float*)d_in[12];
  const float* v1   = (const float*)d_in[13];
  const float* g2   = (const float*)d_in[14];
  const float* be2  = (const float*)d_in[15];
  const float* m2   = (const float*)d_in[16];
  const float* v2   = (const float*)d_in[17];
  const float* a1   = (const float*)d_in[18];
  const float* a2   = (const float*)d_in[19];

  char* ws = (char*)d_ws;
  u8*    act1pad = (u8*)(ws + 0ull);           // fp8 (32,30,30,256) = 7,372,800
  u8*    w1T     = (u8*)(ws + 7372800ull);     // 36 phases x 16KB = 589,824
  u8*    w2T     = (u8*)(ws + 7962624ull);     // 4 phases x 16KB = 65,536
  float* ab      = (float*)(ws + 8028160ull);  // 4 x 256 f32

  float* out = (float*)d_out;

  prep_act_kernel<<<1408, 256, 0, stream>>>(w1, w2, g1, be1, m1, v1, g2, be2, m2, v2,
                                            w1T, w2T, ab, out + (out_size - 1), loss,
                                            x, b11, act1pad);
  fused_kernel<<<224, 512, 0, stream>>>(act1pad, x, w1T, w2T, ab,
                                        b12, a1, b13, b21, b22, a2, b23, out);
}

// Round 12
// 48.382 us; speedup vs baseline: 1.3610x; 1.3610x over previous
//
#include <hip/hip_runtime.h>
#include <hip/hip_bf16.h>

// BasicBlock (ReActNet) fused pipeline, MI355X gfx950.  R12:
// MX-scaled fp8 MFMA (mfma_scale_f32_32x32x64_f8f6f4, fmt=fp8, scales=1.0)
// = 2.14x the plain-fp8 rate. R10 skeleton; wave = 4 m-frags(32px) x 32 och;
// block = 112 real px (padded to 128) x 256 och; 36 phases.
// w1T/w2T repacked [tap][c64][kh][och][32B]; act1pad linear ci.

typedef unsigned short u16;
typedef unsigned char  u8;
typedef unsigned int   u32;
typedef unsigned long long u64;
typedef float f32x4 __attribute__((ext_vector_type(4)));
typedef long  long2v __attribute__((ext_vector_type(2)));
typedef int   v8i  __attribute__((ext_vector_type(8)));
typedef float v16f __attribute__((ext_vector_type(16)));

#define GLD16(gsrc, ldst) \
  __builtin_amdgcn_global_load_lds((__attribute__((address_space(1))) void*)(gsrc), \
                                   (__attribute__((address_space(3))) void*)(ldst), 16, 0, 0)

__device__ __forceinline__ float b2f(u16 u) {
  union { unsigned int i; float f; } c; c.i = ((unsigned int)u) << 16; return c.f;
}
__device__ __forceinline__ u16 f2b(float f) {
  unsigned int u = __builtin_bit_cast(unsigned int, f);
  unsigned int r = (u + 0x7FFFu + ((u >> 16) & 1u)) >> 16;   // RNE
  return (u16)r;
}
__device__ __forceinline__ u8 f2sign8(float v) {   // fp8 e4m3 of sign(v)
  return (v > 0.f) ? 0x38 : ((v < 0.f) ? 0xB8 : 0x00);
}
__device__ __forceinline__ v8i mkv8(long2v a, long2v b) {
  union { long2v l[2]; v8i v; } u; u.l[0] = a; u.l[1] = b; return u.v;
}

// ---- prep(blk<512) + act1(blk>=512) merged ----
// w1T layout: [(tap*4+c64)*2+kh][och 256][32B], sign bytes of ci=c64*64+kh*32+[0,32)
__global__ __launch_bounds__(256) void prep_act_kernel(
    const float* __restrict__ w1, const float* __restrict__ w2,
    const float* __restrict__ g1, const float* __restrict__ be1,
    const float* __restrict__ m1, const float* __restrict__ v1,
    const float* __restrict__ g2, const float* __restrict__ be2,
    const float* __restrict__ m2, const float* __restrict__ v2,
    u8* __restrict__ w1T, u8* __restrict__ w2T,
    float* __restrict__ ab,
    float* __restrict__ lossdst, const float* __restrict__ lossin,
    const float* __restrict__ x, const float* __restrict__ b11,
    u8* __restrict__ act1pad)
{
  __shared__ float wrow[2304];
  __shared__ float red[256];
  __shared__ u8 lds8[112 * 64];
  const int t = threadIdx.x;
  const int blk = blockIdx.x;

  if (blk < 512) {   // ================= prep =================
    float s = 0.f;
    if (blk < 256) {
      const int o = blk;
      const float4* src = (const float4*)(w1 + o * 2304);
#pragma unroll
      for (int i = 0; i < 3; ++i) {
        int c = i * 256 + t;
        if (c < 576) {
          float4 v = src[c];
          wrow[c * 4 + 0] = v.x; wrow[c * 4 + 1] = v.y;
          wrow[c * 4 + 2] = v.z; wrow[c * 4 + 3] = v.w;
          s += fabsf(v.x) + fabsf(v.y) + fabsf(v.z) + fabsf(v.w);
        }
      }
    } else {
      const int o = blk - 256;
      float v = w2[o * 256 + t];
      wrow[t] = v;
      s = fabsf(v);
    }
    red[t] = s;
    __syncthreads();
    for (int st = 128; st > 0; st >>= 1) { if (t < st) red[t] += red[t + st]; __syncthreads(); }
    if (blk < 256) {
      const int o = blk;
      for (int it = t; it < 288; it += 256) {   // (tap, ci-octet)
        int tap = it >> 5, ci8 = it & 31;
        u64 pack = 0;
#pragma unroll
        for (int k = 0; k < 8; ++k)
          pack |= ((u64)f2sign8(wrow[(ci8 * 8 + k) * 9 + tap])) << (8 * k);
        int c64 = ci8 >> 3, kh = (ci8 >> 2) & 1, slot = ci8 & 3;
        *(u64*)(w1T + (size_t)((tap * 4 + c64) * 2 + kh) * 8192 + o * 32 + slot * 8) = pack;
      }
      if (t == 0) {
        float scale = red[0] / 2304.f;
        float inv = g1[o] / sqrtf(v1[o] + 1e-5f);
        ab[o]       = scale * inv;
        ab[256 + o] = be1[o] - m1[o] * inv;
      }
    } else {
      const int o = blk - 256;
      if (t < 32) {
        u64 pack = 0;
#pragma unroll
        for (int k = 0; k < 8; ++k)
          pack |= ((u64)f2sign8(wrow[t * 8 + k])) << (8 * k);
        int c64 = t >> 3, kh = (t >> 2) & 1, slot = t & 3;
        *(u64*)(w2T + (size_t)(c64 * 2 + kh) * 8192 + o * 32 + slot * 8) = pack;
      }
      if (t == 0) {
        float scale = red[0] / 256.f;
        float inv = g2[o] / sqrtf(v2[o] + 1e-5f);
        ab[512 + o] = scale * inv;
        ab[768 + o] = be2[o] - m2[o] * inv;
      }
    }
    if (blk == 0 && t == 0) lossdst[0] = lossin[0];
    return;
  }

  // ================= act1 (linear ci layout) =================
  const int b2i = blk - 512;             // 0..895
  const int pxgrp = b2i % 7;
  const int cgrp  = (b2i / 7) & 3;
  const int img   = b2i / 28;
  const int c0 = cgrp * 64;
  const int p0 = pxgrp * 112;
  const float* xb = x + (size_t)img * 200704;
#pragma unroll
  for (int it = 0; it < 7; ++it) {
    int flat = it * 256 + t;           // c:64 x p4:28
    int c = flat / 28;
    int p = (flat % 28) * 4;
    float4 v4 = *(const float4*)(xb + (size_t)(c0 + c) * 784 + p0 + p);
    float bb = b11[c0 + c];
    lds8[(p + 0) * 64 + c] = f2sign8(v4.x + bb);
    lds8[(p + 1) * 64 + c] = f2sign8(v4.y + bb);
    lds8[(p + 2) * 64 + c] = f2sign8(v4.z + bb);
    lds8[(p + 3) * 64 + c] = f2sign8(v4.w + bb);
  }
  __syncthreads();
#pragma unroll
  for (int it = 0; it < 7; ++it) {
    int flat = it * 256 + t;           // px:112 x c4:16
    int px = flat >> 4;
    int c4 = (flat & 15) * 4;
    u32 v = *(const u32*)(lds8 + px * 64 + c4);
    int pr = (px * 293) >> 13;         // px/28
    int pc = px - 28 * pr;
    size_t dst = ((size_t)img * 900 + (size_t)(pxgrp * 4 + 1 + pr) * 30 + 1 + pc) * 256 + c0 + c4;
    *(u32*)(act1pad + dst) = v;
  }
  if (pxgrp == 0 && cgrp == 0) {
    for (int idx = t; idx < 116 * 64; idx += 256) {
      int bp = idx >> 6;
      int l4 = (idx & 63) * 4;
      int br, bc;
      if (bp < 30)      { br = 0;       bc = bp; }
      else if (bp < 60) { br = 29;      bc = bp - 30; }
      else if (bp < 88) { br = bp - 59; bc = 0; }
      else              { br = bp - 87; bc = 29; }
      *(u32*)(act1pad + ((size_t)img * 900 + br * 30 + bc) * 256 + l4) = 0u;
    }
  }
}

// ---------------- fused conv3x3 + conv1x1, MX-scaled fp8 32x32x64 ----------------
__global__ __launch_bounds__(512, 1) void fused_kernel(
    const u8* __restrict__ act1pad, const float* __restrict__ x,
    const u8* __restrict__ w1T, const u8* __restrict__ w2T,
    const float* __restrict__ ab,
    const float* __restrict__ b12, const float* __restrict__ a1,
    const float* __restrict__ b13, const float* __restrict__ b21,
    const float* __restrict__ b22, const float* __restrict__ a2,
    const float* __restrict__ b23,
    float* __restrict__ dout)
{
  __shared__ __align__(16) u8 win[51200];   // window (46080 staged, +OOB slack); reused for act2

  const int t = threadIdx.x;
  const int w = t >> 6;                // 0..7 -> och group of 32
  const int l = t & 63;
  const int l31 = l & 31;
  const int h32 = l >> 5;              // k-half selector
  const int O = w * 32 + l31;          // this lane's out-channel
  const int pxblk = blockIdx.x;        // 224
  const int img = pxblk / 7;
  const int rowgrp = pxblk % 7;

  // scalar epilogue params (n=1)
  const float al1 = ab[O],       bt1 = ab[256 + O];
  const float al2 = ab[512 + O], bt2 = ab[768 + O];
  const float pA1 = b12[O], pS1 = a1[O], pB1 = b13[O], p21 = b21[O];
  const float pA2 = b22[O], pS2 = a2[O], pB2 = b23[O];

  int basepix[4];
#pragma unroll
  for (int m = 0; m < 4; ++m) {
    int pm = m * 32 + l31;             // 0..127 (112..127 = pad garbage)
    int r = (pm * 293) >> 13;          // pm/28
    basepix[m] = r * 30 + (pm - 28 * r);
  }

  char* wl = (char*)win;

  v16f acc[4];
  v16f zero16 = {0.f,0.f,0.f,0.f,0.f,0.f,0.f,0.f,0.f,0.f,0.f,0.f,0.f,0.f,0.f,0.f};
#pragma unroll
  for (int m = 0; m < 4; ++m) acc[m] = zero16;

  // ---- prologue: stage window (180 px x 256B) with XOR pre-swizzled source ----
  const u8* winsrc = act1pad + ((size_t)img * 900 + (size_t)rowgrp * 120) * 256;
#pragma unroll
  for (int i = 0; i < 5; ++i) {
    int c = i * 512 + t;
    int pix = c >> 4, j = c & 15;
    GLD16((const char*)winsrc + pix * 256 + ((j ^ (pix & 15)) << 4), wl + c * 16);
  }
  if (t < 320) {
    int c = 2560 + t;
    int pix = c >> 4, j = c & 15;
    GLD16((const char*)winsrc + pix * 256 + ((j ^ (pix & 15)) << 4), wl + c * 16);
  }
  asm volatile("s_waitcnt vmcnt(0)" ::: "memory");
  __builtin_amdgcn_s_barrier();

  // ---- loaders / compute ----
  auto LOADB3 = [&](long2v* dst, int s) {     // 32B/lane, coalesced per half-wave
    int sc = (s < 36) ? s : 0;
    const char* base = (const char*)w1T + (size_t)sc * 16384 + h32 * 8192 + O * 32;
    dst[0] = *(const long2v*)(base);
    dst[1] = *(const long2v*)(base + 16);
  };
  auto DSA3 = [&](long2v (*dst)[2], int s) {  // 4 m-frags x 32B
    int sc = (s < 36) ? s : 0;
    int tap = sc >> 2;
    int c64 = sc & 3;
    int ti = (tap * 11) >> 5;                 // tap/3
    int tapoff = ti * 30 + (tap - 3 * ti);
    int off = c64 * 64 + h32 * 32;
#pragma unroll
    for (int m = 0; m < 4; ++m) {
      int wp = basepix[m] + tapoff;
      int sw = (wp & 15) << 4;
      const char* p = wl + wp * 256;
      dst[m][0] = *(const long2v*)(p + ((off)      ^ sw));
      dst[m][1] = *(const long2v*)(p + ((off + 16) ^ sw));
    }
  };
  auto COMP = [&](long2v (*a)[2], const long2v* bv) {
    v8i b8 = mkv8(bv[0], bv[1]);
    __builtin_amdgcn_s_setprio(1);
#pragma unroll
    for (int m = 0; m < 4; ++m)
      acc[m] = __builtin_amdgcn_mfma_scale_f32_32x32x64_f8f6f4(
          mkv8(a[m][0], a[m][1]), b8, acc[m],
          0, 0,                       // cbsz=fp8(A), blgp=fp8(B)
          0, 0x7F7F7F7Fu,             // scale A sel, scales = 1.0
          0, 0x7F7F7F7Fu);            // scale B sel, scales = 1.0
    __builtin_amdgcn_s_setprio(0);
  };

  // ---- conv3x3: 36 phases, A dbuf + B 3-set rotation, no barriers ----
  long2v A0[4][2], A1[4][2];
  long2v b0[2], b1[2], b2[2];
  DSA3(A0, 0); LOADB3(b0, 0); LOADB3(b1, 1);
#pragma unroll 1
  for (int i = 0; i < 6; ++i) {
    int p = i * 6;
    LOADB3(b2, p + 2); DSA3(A1, p + 1); COMP(A0, b0);
    LOADB3(b0, p + 3); DSA3(A0, p + 2); COMP(A1, b1);
    LOADB3(b1, p + 4); DSA3(A1, p + 3); COMP(A0, b2);
    LOADB3(b2, p + 5); DSA3(A0, p + 4); COMP(A1, b0);
    LOADB3(b0, p + 6); DSA3(A1, p + 5); COMP(A0, b1);
    LOADB3(b1, p + 7); DSA3(A0, p + 6); COMP(A1, b2);
  }
  __builtin_amdgcn_s_barrier();      // window reads done -> reuse for act2

  // ---- epilogue 1: out1 = BN(conv)+x(f32) -> bias/PReLU/bias; act2 -> LDS ----
  // C/D row = (reg&3) + 8*(reg>>2) + 4*h32 ; pixel = m*32 + that ; och = O.
  u32 pk[4][4][2];
#pragma unroll
  for (int m = 0; m < 4; ++m) {
#pragma unroll
    for (int rp = 0; rp < 4; ++rp) {
      int pixbase = m * 32 + 8 * rp + 4 * h32;
      int hwm = rowgrp * 112 + pixbase;
      bool valid = (m < 3) || (rp < 2);
      float xv[4] = {0.f, 0.f, 0.f, 0.f};
      if (valid) {
        float4 xr = *(const float4*)(x + ((size_t)(img * 256 + O) * 784 + hwm));
        xv[0] = xr.x; xv[1] = xr.y; xv[2] = xr.z; xv[3] = xr.w;
      }
      float o1v[4];
#pragma unroll
      for (int reg = 0; reg < 4; ++reg) {
        int pix = pixbase + reg;
        float v = acc[m][rp * 4 + reg] * al1 + bt1 + xv[reg];
        float t1 = v + pA1;
        t1 = (t1 > 0.f) ? t1 : pS1 * t1;
        o1v[reg] = t1 + pB1;
        wl[pix * 256 + (O ^ ((pix & 15) << 4))] = f2sign8(o1v[reg] + p21);
      }
      pk[m][rp][0] = (u32)f2b(o1v[0]) | ((u32)f2b(o1v[1]) << 16);
      pk[m][rp][1] = (u32)f2b(o1v[2]) | ((u32)f2b(o1v[3]) << 16);
    }
  }
#pragma unroll
  for (int m = 0; m < 4; ++m) acc[m] = zero16;

  asm volatile("s_waitcnt lgkmcnt(0)" ::: "memory");   // act2 LDS stores complete
  __builtin_amdgcn_s_barrier();

  // ---- conv1x1: 4 phases (K=256), A dbuf + B 2-set rotation ----
  auto LOADB1 = [&](long2v* dst, int sp) {
    const char* base = (const char*)w2T + (size_t)sp * 16384 + h32 * 8192 + O * 32;
    dst[0] = *(const long2v*)(base);
    dst[1] = *(const long2v*)(base + 16);
  };
  auto DSA1 = [&](long2v (*dst)[2], int sp) {
    int off = sp * 64 + h32 * 32;
#pragma unroll
    for (int m = 0; m < 4; ++m) {
      int pm = m * 32 + l31;
      int sw = (pm & 15) << 4;
      const char* p = wl + pm * 256;
      dst[m][0] = *(const long2v*)(p + ((off)      ^ sw));
      dst[m][1] = *(const long2v*)(p + ((off + 16) ^ sw));
    }
  };
  DSA1(A0, 0); LOADB1(b0, 0);
  DSA1(A1, 1); LOADB1(b1, 1); COMP(A0, b0);
  DSA1(A0, 2); LOADB1(b0, 2); COMP(A1, b1);
  DSA1(A1, 3); LOADB1(b1, 3); COMP(A0, b0);
  COMP(A1, b1);

  // ---- epilogue 2: out2 -> dout NCHW f32 ----
#pragma unroll
  for (int m = 0; m < 4; ++m) {
#pragma unroll
    for (int rp = 0; rp < 4; ++rp) {
      bool valid = (m < 3) || (rp < 2);
      if (!valid) continue;
      int pixbase = m * 32 + 8 * rp + 4 * h32;
      int hwm = rowgrp * 112 + pixbase;
      float res[4];
      res[0] = b2f((u16)(pk[m][rp][0] & 0xFFFF));
      res[1] = b2f((u16)(pk[m][rp][0] >> 16));
      res[2] = b2f((u16)(pk[m][rp][1] & 0xFFFF));
      res[3] = b2f((u16)(pk[m][rp][1] >> 16));
      float r4v[4];
#pragma unroll
      for (int reg = 0; reg < 4; ++reg) {
        float v = acc[m][rp * 4 + reg] * al2 + bt2 + res[reg];
        float t1 = v + pA2;
        t1 = (t1 > 0.f) ? t1 : pS2 * t1;
        r4v[reg] = t1 + pB2;
      }
      float4 r4 = {r4v[0], r4v[1], r4v[2], r4v[3]};
      *(float4*)(dout + ((size_t)(img * 256 + O)) * 784 + hwm) = r4;
    }
  }
}

// ---------------- launcher ----------------
extern "C" void kernel_launch(void* const* d_in, const int* in_sizes, int n_in,
                              void* d_out, int out_size, void* d_ws, size_t ws_size,
                              hipStream_t stream) {
  const float* x    = (const float*)d_in[0];
  const float* loss = (const float*)d_in[1];
  const float* b11  = (const float*)d_in[2];
  const float* b12  = (const float*)d_in[3];
  const float* b13  = (const float*)d_in[4];
  const float* b21  = (const float*)d_in[5];
  const float* b22  = (const float*)d_in[6];
  const float* b23  = (const float*)d_in[7];
  const float* w1   = (const float*)d_in[8];
  const float* w2   = (const float*)d_in[9];
  const float* g1   = (const float*)d_in[10];
  const float* be1  = (const float*)d_in[11];
  const float* m1   = (const float*)d_in[12];
  const float* v1   = (const float*)d_in[13];
  const float* g2   = (const float*)d_in[14];
  const float* be2  = (const float*)d_in[15];
  const float* m2   = (const float*)d_in[16];
  const float* v2   = (const float*)d_in[17];
  const float* a1   = (const float*)d_in[18];
  const float* a2   = (const float*)d_in[19];

  char* ws = (char*)d_ws;
  u8*    act1pad = (u8*)(ws + 0ull);           // fp8 (32,30,30,256) = 7,372,800
  u8*    w1T     = (u8*)(ws + 7372800ull);     // 36 x 16KB = 589,824
  u8*    w2T     = (u8*)(ws + 7962624ull);     // 4 x 16KB = 65,536
  float* ab      = (float*)(ws + 8028160ull);  // 4 x 256 f32

  float* out = (float*)d_out;

  prep_act_kernel<<<1408, 256, 0, stream>>>(w1, w2, g1, be1, m1, v1, g2, be2, m2, v2,
                                            w1T, w2T, ab, out + (out_size - 1), loss,
                                            x, b11, act1pad);
  fused_kernel<<<224, 512, 0, stream>>>(act1pad, x, w1T, w2T, ab,
                                        b12, a1, b13, b21, b22, a2, b23, out);
}